// Round 9
// baseline (407.877 us; speedup 1.0000x reference)
//
#include <hip/hip_runtime.h>

typedef __bf16 bf16x8 __attribute__((ext_vector_type(8)));
typedef float f32x4 __attribute__((ext_vector_type(4)));
typedef unsigned short u16;

__device__ __forceinline__ float b2f(u16 u) {
  union { unsigned int i; float f; } v; v.i = ((unsigned int)u) << 16; return v.f;
}
__device__ __forceinline__ u16 f2b(float f) {
  union { float f; unsigned int i; } v; v.f = f;
  unsigned int x = v.i;
  x += 0x7fffu + ((x >> 16) & 1u);   // round-to-nearest-even
  return (u16)(x >> 16);
}
// fast tanh-gelu (validated R4-R6: absmax 0.047)
__device__ __forceinline__ float gelu_f(float x) {
  float x2 = x * x;
  float p = x * (1.5957691216f + 0.0713548162f * x2);
  float e = __expf(p);
  float r = __builtin_amdgcn_rcpf(1.0f + e);
  return x - x * r;
}
__device__ __forceinline__ void async16(const u16* g, u16* l) {
  __builtin_amdgcn_global_load_lds(
      (const __attribute__((address_space(1))) void*)g,
      (__attribute__((address_space(3))) void*)l, 16, 0, 0);
}
// XCD-aware supertile swizzle (R6; neutral at worst)
__device__ __forceinline__ void swz(int& bn, int& bm, int& bz) {
  int gx = (int)gridDim.x, gy = (int)gridDim.y;
  int flat = (int)(blockIdx.x + gridDim.x * (blockIdx.y + gridDim.y * blockIdx.z));
  int seq = flat >> 3;
  int nbm = gy >> 3;
  bm = (flat & 7) * nbm + seq % nbm;
  int rest = seq / nbm;
  bn = rest % gx;
  bz = rest / gx;
}

union U4 { uint4 u; u16 s[8]; };

// ---------------- prep: cvt9 + cvtT8 + ln1 fused into ONE launch ----------------
// The three phases are mutually independent (weights cvt, val-weights cvtT,
// layernorm of x). Branch on flat block id: [0,9216) cvt9, [9216,17408) cvtT8,
// [17408,18432) ln1. Removes 2 serial launch boundaries and overlaps the
// memory-bound tails.
__global__ __launch_bounds__(256) void prep_kernel(
    const float* __restrict__ qk, const float* __restrict__ kk,
    const float* __restrict__ vk, const float* __restrict__ pk,
    const float* __restrict__ fk, u16* __restrict__ w, float* __restrict__ ssqz,
    const float* __restrict__ qv, const float* __restrict__ kv,
    const float* __restrict__ vv, const float* __restrict__ pv,
    const float* __restrict__ fv, u16* __restrict__ valsT, u16* __restrict__ fvT,
    const float* __restrict__ x, const float* __restrict__ lnw,
    const float* __restrict__ lnb, u16* __restrict__ xn) {
  __shared__ float t[32][33];
  int id = (int)blockIdx.x;
  int tid = threadIdx.x;
  if (id < 9216) {
    // ---- cvt9: fp32 -> bf16 K-major weights + ssq zero ----
    int z = id >> 10;
    int i = (id & 1023) * 256 + tid;
    if (z == 8) {
      if (i < 20480) ssqz[i] = 0.f;
      return;
    }
    const float* in = (z == 0) ? qk : (z == 1) ? kk : (z == 2) ? vk : (z == 3) ? pk
                      : fk + (size_t)(z - 4) * 1048576;
    u16* o = w + (size_t)z * 1048576;
    float4 f = ((const float4*)in)[i];
    ushort4 s;
    s.x = f2b(f.x); s.y = f2b(f.y); s.z = f2b(f.z); s.w = f2b(f.w);
    ((ushort4*)o)[i] = s;
  } else if (id < 17408) {
    // ---- cvtT8: fp32 [R,1024] -> bf16 transposed val weights ----
    int rid = id - 9216;
    int bc = rid & 31, br = (rid >> 5) & 31, z = rid >> 10;
    const float* in; u16* o; int Rout, rowoff;
    if (z < 4) {
      in = (z == 0) ? qv : (z == 1) ? kv : (z == 2) ? vv : pv;
      o = valsT + (size_t)z * 1048576; Rout = 1024; rowoff = 0;
    } else {
      in = fv + (size_t)(z - 4) * 1048576;
      o = fvT; Rout = 4096; rowoff = (z - 4) * 1024;
    }
    int r = tid >> 5, cc = tid & 31;
    #pragma unroll
    for (int i = 0; i < 4; ++i)
      t[r + i * 8][cc] = in[(size_t)(br * 32 + r + i * 8) * 1024 + bc * 32 + cc];
    __syncthreads();
    #pragma unroll
    for (int i = 0; i < 4; ++i)
      o[(size_t)(bc * 32 + r + i * 8) * Rout + rowoff + br * 32 + cc] = f2b(t[cc][r + i * 8]);
  } else {
    // ---- ln1: wave-per-row, shuffle-only ----
    int wv = tid >> 6, lane = tid & 63;
    int row = (id - 17408) * 4 + wv;
    const float* xr = x + (size_t)row * 1024;
    float4 v[4];
    float s = 0.f, s2 = 0.f;
    #pragma unroll
    for (int i = 0; i < 4; ++i) {
      v[i] = ((const float4*)xr)[lane + 64 * i];
      s += v[i].x + v[i].y + v[i].z + v[i].w;
      s2 += v[i].x * v[i].x + v[i].y * v[i].y + v[i].z * v[i].z + v[i].w * v[i].w;
    }
    #pragma unroll
    for (int m = 1; m < 64; m <<= 1) { s += __shfl_xor(s, m); s2 += __shfl_xor(s2, m); }
    float mu = s * (1.0f / 1024.0f);
    float inv = rsqrtf(s2 * (1.0f / 1024.0f) - mu * mu + 1e-5f);
    u16* orow = xn + (size_t)row * 1024;
    #pragma unroll
    for (int i = 0; i < 4; ++i) {
      int c = (lane + 64 * i) * 4;
      ushort4 o;
      o.x = f2b((v[i].x - mu) * inv * lnw[c]     + lnb[c]);
      o.y = f2b((v[i].y - mu) * inv * lnw[c + 1] + lnb[c + 1]);
      o.z = f2b((v[i].z - mu) * inv * lnw[c + 2] + lnb[c + 2]);
      o.w = f2b((v[i].w - mu) * inv * lnw[c + 3] + lnb[c + 3]);
      ((ushort4*)orow)[lane + 64 * i] = o;
    }
  }
}

// ---------------- LayerNorm: wave-per-row, shuffle-only (ln2) ----------------
__global__ __launch_bounds__(256) void ln_kernel(const float* __restrict__ x,
    const float* __restrict__ w, const float* __restrict__ b, u16* __restrict__ out) {
  int wv = threadIdx.x >> 6, lane = threadIdx.x & 63;
  int row = blockIdx.x * 4 + wv;
  const float* xr = x + (size_t)row * 1024;
  float4 v[4];
  float s = 0.f, s2 = 0.f;
  #pragma unroll
  for (int i = 0; i < 4; ++i) {
    v[i] = ((const float4*)xr)[lane + 64 * i];
    s += v[i].x + v[i].y + v[i].z + v[i].w;
    s2 += v[i].x * v[i].x + v[i].y * v[i].y + v[i].z * v[i].z + v[i].w * v[i].w;
  }
  #pragma unroll
  for (int m = 1; m < 64; m <<= 1) { s += __shfl_xor(s, m); s2 += __shfl_xor(s2, m); }
  float mu = s * (1.0f / 1024.0f);
  float inv = rsqrtf(s2 * (1.0f / 1024.0f) - mu * mu + 1e-5f);
  u16* orow = out + (size_t)row * 1024;
  #pragma unroll
  for (int i = 0; i < 4; ++i) {
    int c = (lane + 64 * i) * 4;
    ushort4 o;
    o.x = f2b((v[i].x - mu) * inv * w[c]     + b[c]);
    o.y = f2b((v[i].y - mu) * inv * w[c + 1] + b[c + 1]);
    o.z = f2b((v[i].z - mu) * inv * w[c + 2] + b[c + 2]);
    o.w = f2b((v[i].w - mu) * inv * w[c + 3] + b[c + 3]);
    ((ushort4*)orow)[lane + 64 * i] = o;
  }
}

// ============ 3-deep counted-vmcnt 128-tile GEMMs (R5-exact symmetric pipeline) ============
// LDS triple-buffer; raw s_barrier + counted s_waitcnt vmcnt(G) per K-step so
// staging loads issued 2 iterations ago are waited (latency hidden), never a
// full vmcnt(0) drain except the last step. T2 swizzle (conflicts=0):
// staging pre-swizzles global source col (slot ^ (lane>>3)&3, linear LDS dest);
// reads use rq = quad ^ ((l16>>1)&3).
// Race safety: per-wave vmcnt + s_barrier => all buf[t] loads landed before any
// read; stage of buf[(t+2)%3] issued AFTER barrier(t), and every wave reaching
// barrier(t) has completed its t-1 ds_reads (lgkm drained by MFMA consumers).

// ---------------- key-GEMM: gelu + bf16 store + ssq atomic ----------------
template <int TM>
__global__ __launch_bounds__(256) void gemm_key(
    const u16* __restrict__ A, size_t sAz,
    const u16* __restrict__ B, size_t sBz,
    u16* __restrict__ C, size_t sCz,
    float* __restrict__ ssqb, size_t sSz,
    int N, int K, float alpha) {
  constexpr int AI = TM / 32;
  constexpr int G = TM / 64 + 2;                    // staging loads per thread
  __shared__ __align__(16) u16 As[3][TM * 32];
  __shared__ __align__(16) u16 Bs[3][128 * 32];
  int bn, bm, bz;
  swz(bn, bm, bz);
  const u16* Ab = A + (size_t)bz * sAz + (size_t)bm * TM * K;
  const u16* Bb = B + (size_t)bz * sBz + (size_t)bn * 128 * K;
  int tid = threadIdx.x, lane = tid & 63, wv = tid >> 6;
  int quad = lane >> 4, l16 = lane & 15;
  int lr = lane >> 2;
  int lcs = ((lane & 3) ^ ((lane >> 3) & 3)) * 8;   // pre-swizzled source col
  int rq = quad ^ ((l16 >> 1) & 3);                 // swizzled read slot
  int wm = wv >> 1, wn = wv & 1;
  int RB = wm * (TM / 2), CB = wn * 64;
  auto STAGE = [&](int k0, int buf) {
    #pragma unroll
    for (int t = 0; t < TM / 64; ++t) {
      int ia = wv * (TM / 64) + t;
      async16(Ab + (size_t)(ia * 16 + lr) * K + k0 + lcs, &As[buf][ia * 512]);
    }
    #pragma unroll
    for (int t = 0; t < 2; ++t) {
      int ib = wv * 2 + t;
      async16(Bb + (size_t)(ib * 16 + lr) * K + k0 + lcs, &Bs[buf][ib * 512]);
    }
  };
  f32x4 zero = {0.f, 0.f, 0.f, 0.f};
  f32x4 acc[AI][4];
  #pragma unroll
  for (int i = 0; i < AI; ++i)
    #pragma unroll
    for (int j = 0; j < 4; ++j) acc[i][j] = zero;
  int NT = K >> 5;
  STAGE(0, 0);
  STAGE(32, 1);
  int cur = 0;
  for (int t = 0; t < NT; ++t) {
    if (t + 1 < NT) asm volatile("s_waitcnt vmcnt(%0)" :: "i"(G) : "memory");
    else            asm volatile("s_waitcnt vmcnt(0)" ::: "memory");
    __builtin_amdgcn_s_barrier();
    __builtin_amdgcn_sched_barrier(0);
    bf16x8 af[AI], bf[4];
    #pragma unroll
    for (int i = 0; i < AI; ++i)
      af[i] = *(const bf16x8*)&As[cur][(RB + i * 16 + l16) * 32 + rq * 8];
    #pragma unroll
    for (int j = 0; j < 4; ++j)
      bf[j] = *(const bf16x8*)&Bs[cur][(CB + j * 16 + l16) * 32 + rq * 8];
    if (t + 2 < NT) {
      int nb = cur + 2; if (nb >= 3) nb -= 3;
      STAGE((t + 2) * 32, nb);
    }
    #pragma unroll
    for (int i = 0; i < AI; ++i)
      #pragma unroll
      for (int j = 0; j < 4; ++j)
        acc[i][j] = __builtin_amdgcn_mfma_f32_16x16x32_bf16(af[i], bf[j], acc[i][j], 0, 0, 0);
    cur = (cur == 2) ? 0 : cur + 1;
  }
  #pragma unroll
  for (int i = 0; i < AI; ++i) {
    int rbase = bm * TM + RB + i * 16 + quad * 4;
    float srow[4] = {0.f, 0.f, 0.f, 0.f};
    #pragma unroll
    for (int j = 0; j < 4; ++j) {
      int c = bn * 128 + CB + j * 16 + l16;
      #pragma unroll
      for (int reg = 0; reg < 4; ++reg) {
        float g = gelu_f(acc[i][j][reg] * alpha);
        srow[reg] += g * g;
        C[(size_t)bz * sCz + (size_t)(rbase + reg) * N + c] = f2b(g);
      }
    }
    #pragma unroll
    for (int reg = 0; reg < 4; ++reg) {
      float s = srow[reg];
      s += __shfl_xor(s, 1); s += __shfl_xor(s, 2);
      s += __shfl_xor(s, 4); s += __shfl_xor(s, 8);
      if (l16 == 0) atomicAdd(&ssqb[bz * sSz + rbase + reg], s);
    }
  }
}

// ---------------- FFN-key GEMM v2: 128x256 block, 64x128 wave tile ----------------
// LDS-BW is the measured limiter (R8: MfmaUtil 23% matches 85 B/cyc ds_read
// ceiling at 64x64 wave tiles). 64x128 wave tile cuts LDS bytes/FLOP by 1.33x.
// A2(8KB)/B3(16KB) = 64KB LDS -> 2 blocks/CU; grid 16x32 = 512 = exactly full.
// vmcnt ledger: iter t issues A(t+1)[2] then B(t+2)[4]; wait leaves B(t+1) ->
// vmcnt(4); last iter vmcnt(0). Standalone function (rule #19 guard).
__global__ __launch_bounds__(256, 2) void gemm_fkey(
    const u16* __restrict__ A,
    const u16* __restrict__ B,
    u16* __restrict__ C,
    float* __restrict__ ssqb,
    int N, int K, float alpha) {
  __shared__ __align__(16) u16 As[2][128 * 32];
  __shared__ __align__(16) u16 Bs[3][256 * 32];
  int bn, bm, bz;
  swz(bn, bm, bz);
  const u16* Ab = A + (size_t)bm * 128 * K;
  const u16* Bb = B + (size_t)bn * 256 * K;
  int tid = threadIdx.x, lane = tid & 63, wv = tid >> 6;
  int quad = lane >> 4, l16 = lane & 15;
  int lr = lane >> 2;
  int lcs = ((lane & 3) ^ ((lane >> 3) & 3)) * 8;
  int rq = quad ^ ((l16 >> 1) & 3);
  int wm = wv >> 1, wn = wv & 1;
  int RB = wm * 64, CB = wn * 128;
  auto STAGE_A = [&](int k0, int buf) {
    #pragma unroll
    for (int t = 0; t < 2; ++t) {
      int ia = wv * 2 + t;
      async16(Ab + (size_t)(ia * 16 + lr) * K + k0 + lcs, &As[buf][ia * 512]);
    }
  };
  auto STAGE_B = [&](int k0, int buf) {
    #pragma unroll
    for (int t = 0; t < 4; ++t) {
      int ib = wv * 4 + t;
      async16(Bb + (size_t)(ib * 16 + lr) * K + k0 + lcs, &Bs[buf][ib * 512]);
    }
  };
  f32x4 zero = {0.f, 0.f, 0.f, 0.f};
  f32x4 acc[4][8];
  #pragma unroll
  for (int i = 0; i < 4; ++i)
    #pragma unroll
    for (int j = 0; j < 8; ++j) acc[i][j] = zero;
  int NT = K >> 5;
  STAGE_A(0, 0);
  STAGE_B(0, 0);
  STAGE_B(32, 1);
  int cb = 0;
  for (int t = 0; t < NT; ++t) {
    if (t + 1 < NT) asm volatile("s_waitcnt vmcnt(4)" ::: "memory");
    else            asm volatile("s_waitcnt vmcnt(0)" ::: "memory");
    __builtin_amdgcn_s_barrier();
    __builtin_amdgcn_sched_barrier(0);
    bf16x8 af[4], bf[8];
    #pragma unroll
    for (int i = 0; i < 4; ++i)
      af[i] = *(const bf16x8*)&As[t & 1][(RB + i * 16 + l16) * 32 + rq * 8];
    #pragma unroll
    for (int j = 0; j < 8; ++j)
      bf[j] = *(const bf16x8*)&Bs[cb][(CB + j * 16 + l16) * 32 + rq * 8];
    if (t + 1 < NT) STAGE_A((t + 1) * 32, (t + 1) & 1);
    if (t + 2 < NT) {
      int nb = cb + 2; if (nb >= 3) nb -= 3;
      STAGE_B((t + 2) * 32, nb);
    }
    #pragma unroll
    for (int i = 0; i < 4; ++i)
      #pragma unroll
      for (int j = 0; j < 8; ++j)
        acc[i][j] = __builtin_amdgcn_mfma_f32_16x16x32_bf16(af[i], bf[j], acc[i][j], 0, 0, 0);
    cb = (cb == 2) ? 0 : cb + 1;
  }
  #pragma unroll
  for (int i = 0; i < 4; ++i) {
    int rbase = bm * 128 + RB + i * 16 + quad * 4;
    float srow[4] = {0.f, 0.f, 0.f, 0.f};
    #pragma unroll
    for (int j = 0; j < 8; ++j) {
      int c = bn * 256 + CB + j * 16 + l16;
      #pragma unroll
      for (int reg = 0; reg < 4; ++reg) {
        float g = gelu_f(acc[i][j][reg] * alpha);
        srow[reg] += g * g;
        C[(size_t)(rbase + reg) * N + c] = f2b(g);
      }
    }
    #pragma unroll
    for (int reg = 0; reg < 4; ++reg) {
      float s = srow[reg];
      s += __shfl_xor(s, 1); s += __shfl_xor(s, 2);
      s += __shfl_xor(s, 4); s += __shfl_xor(s, 8);
      if (l16 == 0) atomicAdd(&ssqb[rbase + reg], s);
    }
  }
}

// ---------------- val-GEMM ----------------
// MODE 0: bf16 store, *scale (ROT: fused rotary for bz<2, head cols 0..15)
// MODE 1: f32 store, *scale + res ; MODE 2: f32 raw partial (split-K)
template <int TM, int MODE, bool ROT>
__global__ __launch_bounds__(256) void gemm_val(
    const u16* __restrict__ A, size_t sAz,
    const u16* __restrict__ B, size_t sBz,
    void* __restrict__ C, size_t sCz,
    const float* __restrict__ ssqb, size_t sSz,
    int N, int K, int kzs, int klen, float sqrtP, const float* __restrict__ res) {
  constexpr int AI = TM / 32;
  constexpr int G = TM / 64 + 2;
  __shared__ __align__(16) u16 As[3][TM * 32];
  __shared__ __align__(16) u16 Bs[3][128 * 32];
  int bn, bm, bz;
  swz(bn, bm, bz);
  const u16* Ab = A + (size_t)bz * sAz + (size_t)bm * TM * K;
  const u16* Bb = B + (size_t)bz * sBz + (size_t)bn * 128 * K;
  int tid = threadIdx.x, lane = tid & 63, wv = tid >> 6;
  int quad = lane >> 4, l16 = lane & 15;
  int lr = lane >> 2;
  int lcs = ((lane & 3) ^ ((lane >> 3) & 3)) * 8;   // pre-swizzled source col
  int rq = quad ^ ((l16 >> 1) & 3);                 // swizzled read slot
  int wm = wv >> 1, wn = wv & 1;
  int RB = wm * (TM / 2), CB = wn * 64;
  int kb0 = bz * kzs;
  auto STAGE = [&](int k0, int buf) {
    #pragma unroll
    for (int t = 0; t < TM / 64; ++t) {
      int ia = wv * (TM / 64) + t;
      async16(Ab + (size_t)(ia * 16 + lr) * K + kb0 + k0 + lcs, &As[buf][ia * 512]);
    }
    #pragma unroll
    for (int t = 0; t < 2; ++t) {
      int ib = wv * 2 + t;
      async16(Bb + (size_t)(ib * 16 + lr) * K + kb0 + k0 + lcs, &Bs[buf][ib * 512]);
    }
  };
  f32x4 zero = {0.f, 0.f, 0.f, 0.f};
  f32x4 acc[AI][4];
  #pragma unroll
  for (int i = 0; i < AI; ++i)
    #pragma unroll
    for (int j = 0; j < 4; ++j) acc[i][j] = zero;
  int NT = klen >> 5;
  STAGE(0, 0);
  STAGE(32, 1);
  int cur = 0;
  for (int t = 0; t < NT; ++t) {
    if (t + 1 < NT) asm volatile("s_waitcnt vmcnt(%0)" :: "i"(G) : "memory");
    else            asm volatile("s_waitcnt vmcnt(0)" ::: "memory");
    __builtin_amdgcn_s_barrier();
    __builtin_amdgcn_sched_barrier(0);
    bf16x8 af[AI], bf[4];
    #pragma unroll
    for (int i = 0; i < AI; ++i)
      af[i] = *(const bf16x8*)&As[cur][(RB + i * 16 + l16) * 32 + rq * 8];
    #pragma unroll
    for (int j = 0; j < 4; ++j)
      bf[j] = *(const bf16x8*)&Bs[cur][(CB + j * 16 + l16) * 32 + rq * 8];
    if (t + 2 < NT) {
      int nb = cur + 2; if (nb >= 3) nb -= 3;
      STAGE((t + 2) * 32, nb);
    }
    #pragma unroll
    for (int i = 0; i < AI; ++i)
      #pragma unroll
      for (int j = 0; j < 4; ++j)
        acc[i][j] = __builtin_amdgcn_mfma_f32_16x16x32_bf16(af[i], bf[j], acc[i][j], 0, 0, 0);
    cur = (cur == 2) ? 0 : cur + 1;
  }
  #pragma unroll
  for (int i = 0; i < AI; ++i) {
    int rbase = bm * TM + RB + i * 16 + quad * 4;
    float sc[4];
    if (MODE < 2) {
      #pragma unroll
      for (int reg = 0; reg < 4; ++reg)
        sc[reg] = sqrtP * rsqrtf(ssqb[bz * sSz + rbase + reg]);
    }
    #pragma unroll
    for (int j = 0; j < 4; ++j) {
      int c = bn * 128 + CB + j * 16 + l16;
      #pragma unroll
      for (int reg = 0; reg < 4; ++reg) {
        float v = acc[i][j][reg];
        size_t idx = (size_t)(rbase + reg) * N + c;
        if (MODE == 0) {
          float vs = v * sc[reg];
          if (ROT && j == 0) {   // cols c%64 = l16 < 16: the rotary dims of each head
            float prt = __shfl_xor(vs, 8);
            if (bz < 2) {
              int seq = (rbase + reg) & 2047;
              float fr = exp2f((float)(l16 & 7) * -1.66096404744368f);  // 10000^-(i/8)
              float ang = (float)seq * fr;
              float c_ = __cosf(ang), s_ = __sinf(ang);
              vs = (l16 < 8) ? (vs * c_ - prt * s_) : (vs * c_ + prt * s_);
            }
          }
          ((u16*)C)[(size_t)bz * sCz + idx] = f2b(vs);
        } else if (MODE == 1) {
          ((float*)C)[idx] = v * sc[reg] + res[idx];
        } else {
          ((float*)C)[(size_t)bz * sCz + idx] = v;
        }
      }
    }
  }
}

// ---------------- per-head V transpose + PV-slot permutation ----------------
__global__ __launch_bounds__(256) void vt_kernel(const u16* __restrict__ vb,
                                                 u16* __restrict__ vT) {
  __shared__ __align__(16) u16 T[64][72];
  int st = blockIdx.x, bh = blockIdx.y;
  int b = bh >> 4, h = bh & 15;
  int tid = threadIdx.x;
  #pragma unroll
  for (int i = 0; i < 2; ++i) {
    int l = tid + 256 * i;
    int s = l >> 3, dc = l & 7;
    *(uint4*)&T[s][dc * 8] =
        *(const uint4*)(vb + (size_t)(b * 2048 + st * 64 + s) * 1024 + h * 64 + dc * 8);
  }
  __syncthreads();
  #pragma unroll
  for (int i = 0; i < 2; ++i) {
    int l = tid + 256 * i;
    int d = l >> 3, scid = l & 7;
    int blk = (scid >> 2) * 32;
    int qq = (scid & 3) * 4;
    U4 u;
    #pragma unroll
    for (int j = 0; j < 8; ++j)
      u.s[j] = T[blk + (j >> 2) * 16 + qq + (j & 3)][d];
    *(uint4*)(vT + ((size_t)bh * 64 + d) * 2048 + st * 64 + scid * 8) = u.u;
  }
}

// ---------------- fused causal attention, register-resident P ----------------
// LDS tiles stored with T2 XOR swizzle: staging pre-swizzles the GLOBAL source
// column ((lane&7)^row&7; linear global_load_lds dest), reads XOR the u16
// offset with (row&7)<<3 -> conflict-free ds_read_b128 (was 32-way).
__global__ __launch_bounds__(256) void attn_kernel(
    const u16* __restrict__ qb, const u16* __restrict__ kb,
    const u16* __restrict__ vT, u16* __restrict__ ob) {
  __shared__ __align__(16) u16 Qs[64 * 64];       // 8 KB
  __shared__ __align__(16) u16 Ks[2][64 * 64];    // 16 KB
  __shared__ __align__(16) u16 Vts[2][64 * 64];   // 16 KB
  int bh = blockIdx.x;
  int qt = 31 - (int)blockIdx.y;                  // LPT: heavy tiles first
  int b = bh >> 4, h = bh & 15;
  const u16* qp = qb + (size_t)b * 2048 * 1024 + h * 64;
  const u16* kp = kb + (size_t)b * 2048 * 1024 + h * 64;
  const u16* vp = vT + (size_t)bh * 64 * 2048;
  int tid = threadIdx.x, lane = tid & 63, wv = tid >> 6;
  int quad = lane >> 4, l16 = lane & 15;
  int lr8 = lane >> 3;
  int lc8s = ((lane & 7) ^ lr8) * 8;              // pre-swizzled source column
  int rx = (l16 & 7) << 3;                        // read-side inverse XOR
  int MR = wv * 16;
  int nkt = qt + 1;
  #pragma unroll
  for (int t = 0; t < 2; ++t) {
    int idx = wv * 2 + t;
    async16(qp + (size_t)(qt * 64 + idx * 8 + lr8) * 1024 + lc8s, &Qs[idx * 512]);
    async16(kp + (size_t)(idx * 8 + lr8) * 1024 + lc8s, &Ks[0][idx * 512]);
    async16(vp + (size_t)(idx * 8 + lr8) * 2048 + lc8s, &Vts[0][idx * 512]);
  }
  f32x4 zero = {0.f, 0.f, 0.f, 0.f};
  f32x4 oacc[4];
  #pragma unroll
  for (int dn = 0; dn < 4; ++dn) oacc[dn] = zero;
  float ssql = 0.f;
  bf16x8 bq0 = {}, bq1 = {};
  for (int kt = 0, cur = 0; kt < nkt; ++kt, cur ^= 1) {
    __syncthreads();
    if (kt == 0) {
      bq0 = *(const bf16x8*)&Qs[((MR + l16) * 64 + quad * 8) ^ rx];
      bq1 = *(const bf16x8*)&Qs[((MR + l16) * 64 + 32 + quad * 8) ^ rx];
    }
    if (kt + 1 < nkt) {
      #pragma unroll
      for (int t = 0; t < 2; ++t) {
        int idx = wv * 2 + t;
        async16(kp + (size_t)((kt + 1) * 64 + idx * 8 + lr8) * 1024 + lc8s, &Ks[cur ^ 1][idx * 512]);
        async16(vp + (size_t)(idx * 8 + lr8) * 2048 + (kt + 1) * 64 + lc8s, &Vts[cur ^ 1][idx * 512]);
      }
    }
    bool dg = (kt == qt);
    #pragma unroll
    for (int kc = 0; kc < 2; ++kc) {
      bf16x8 pf;
      #pragma unroll
      for (int snh = 0; snh < 2; ++snh) {
        int sn = kc * 2 + snh;
        bf16x8 ak0 = *(const bf16x8*)&Ks[cur][((sn * 16 + l16) * 64 + quad * 8) ^ rx];
        bf16x8 ak1 = *(const bf16x8*)&Ks[cur][((sn * 16 + l16) * 64 + 32 + quad * 8) ^ rx];
        f32x4 st = zero;
        st = __builtin_amdgcn_mfma_f32_16x16x32_bf16(ak0, bq0, st, 0, 0, 0);
        st = __builtin_amdgcn_mfma_f32_16x16x32_bf16(ak1, bq1, st, 0, 0, 0);
        #pragma unroll
        for (int r = 0; r < 4; ++r) {
          float gl = gelu_f(st[r] * 0.125f);
          if (dg && (sn * 16 + quad * 4 + r > MR + l16)) gl = 0.f;
          ssql += gl * gl;
          pf[snh * 4 + r] = (__bf16)gl;            // v_cvt_pk_bf16_f32 pairs
        }
      }
      #pragma unroll
      for (int dn = 0; dn < 4; ++dn) {
        bf16x8 bv = *(const bf16x8*)&Vts[cur][((dn * 16 + l16) * 64 + kc * 32 + quad * 8) ^ rx];
        oacc[dn] = __builtin_amdgcn_mfma_f32_16x16x32_bf16(pf, bv, oacc[dn], 0, 0, 0);
      }
    }
  }
  ssql += __shfl_xor(ssql, 16);
  ssql += __shfl_xor(ssql, 32);
  float sc = 45.254834f * rsqrtf(ssql);
  #pragma unroll
  for (int dn = 0; dn < 4; ++dn)
    #pragma unroll
    for (int r = 0; r < 4; ++r) {
      float scr = __shfl(sc, quad * 4 + r);
      int row = qt * 64 + MR + quad * 4 + r;
      int col = h * 64 + dn * 16 + l16;
      ob[(size_t)(b * 2048 + row) * 1024 + col] = f2b(oacc[dn][r] * scr);
    }
}

// ---------------- finalize: out = x1 + 64*rsqrt(ssq)[row] * (p0+p1) ----------------
__global__ __launch_bounds__(256) void fin_kernel(
    const float* __restrict__ p0, const float* __restrict__ p1,
    const float* __restrict__ x1, const float* __restrict__ ssqf,
    float* __restrict__ out) {
  int row = blockIdx.x, t = threadIdx.x;
  float s = 64.0f * rsqrtf(ssqf[row]);
  size_t base = (size_t)row * 1024 + t * 4;
  float4 a = *(const float4*)(p0 + base);
  float4 b = *(const float4*)(p1 + base);
  float4 r = *(const float4*)(x1 + base);
  float4 o;
  o.x = r.x + s * (a.x + b.x); o.y = r.y + s * (a.y + b.y);
  o.z = r.z + s * (a.z + b.z); o.w = r.w + s * (a.w + b.w);
  *(float4*)(out + base) = o;
}

extern "C" void kernel_launch(void* const* d_in, const int* in_sizes, int n_in,
                              void* d_out, int out_size, void* d_ws, size_t ws_size,
                              hipStream_t stream) {
  const float* x    = (const float*)d_in[0];
  const float* ln1w = (const float*)d_in[1];
  const float* ln1b = (const float*)d_in[2];
  const float* ln2w = (const float*)d_in[3];
  const float* ln2b = (const float*)d_in[4];
  const float* qk   = (const float*)d_in[5];
  const float* qv   = (const float*)d_in[6];
  const float* kk   = (const float*)d_in[7];
  const float* kv   = (const float*)d_in[8];
  const float* vk   = (const float*)d_in[9];
  const float* vv   = (const float*)d_in[10];
  const float* pk   = (const float*)d_in[11];
  const float* pv   = (const float*)d_in[12];
  const float* fk   = (const float*)d_in[13];
  const float* fv   = (const float*)d_in[14];
  float* out = (float*)d_out;

  const size_t M1 = 1048576;
  u16* w = (u16*)d_ws;
  u16* wkeys  = w;                  // 0..3M qk,kk,vk | p0 covers 0..8M at ffn-val
  u16* wpk    = w + 3 * M1;
  u16* wfk    = w + 4 * M1;         // 4..8M
  u16* wvalsT = w + 8 * M1;         // 8..12M qvT,kvT,vvT,pvT
  u16* wpvT   = w + 11 * M1;
  u16* wfvT   = w + 12 * M1;        // 12..16M
  u16* xn     = w + 16 * M1;        // 16..20M
  u16* gq     = w + 20 * M1;        // qkv ghat z-stride 4M: 20,24,28
  u16* ob     = w + 20 * M1;        // attn out (gq z=0 dead)
  u16* vT     = w + 24 * M1;        // permuted V (gq z=1 dead)
  u16* gp     = w + 28 * M1;        // proj ghat (gq z=2 dead)
  u16* gf     = w + 20 * M1;        // ffn ghat 20..36M (ob/vT/gp dead)
  u16* qb     = w + 36 * M1;        // | p1 covers 36..44M at ffn-val
  u16* kb     = w + 40 * M1;
  u16* vb     = w + 44 * M1;
  float* ssq_qkv  = (float*)(w + 48 * M1);   // ssq region, never clobbered
  float* ssq_proj = ssq_qkv + 12288;
  float* ssq_ffn  = ssq_qkv + 16384;
  float* x1 = (float*)(w + 52 * M1);         // 52..60M
  float* p0 = (float*)w;
  float* p1 = (float*)(w + 36 * M1);

  dim3 blk(256);
  prep_kernel<<<18432, blk, 0, stream>>>(
      qk, kk, vk, pk, fk, w, ssq_qkv,
      qv, kv, vv, pv, fv, wvalsT, wfvT,
      x, ln1w, ln1b, xn);

  gemm_key<128><<<dim3(8, 32, 3), blk, 0, stream>>>(
      xn, 0, wkeys, M1, gq, 4 * M1, ssq_qkv, 4096, 1024, 1024, 32.0f);
  gemm_val<128, 0, true><<<dim3(8, 32, 3), blk, 0, stream>>>(
      gq, 4 * M1, wvalsT, M1, qb, 4 * M1, ssq_qkv, 4096, 1024, 1024, 0, 1024, 32.0f, nullptr);

  vt_kernel<<<dim3(32, 32), blk, 0, stream>>>(vb, vT);
  attn_kernel<<<dim3(32, 32), blk, 0, stream>>>(qb, kb, vT, ob);

  gemm_key<64><<<dim3(8, 64, 1), blk, 0, stream>>>(
      ob, 0, wpk, 0, gp, 0, ssq_proj, 0, 1024, 1024, 32.0f);
  gemm_val<64, 1, false><<<dim3(8, 64, 1), blk, 0, stream>>>(
      gp, 0, wpvT, 0, x1, 0, ssq_proj, 0, 1024, 1024, 0, 1024, 32.0f, x);

  ln_kernel<<<1024, blk, 0, stream>>>(x1, ln2w, ln2b, xn);
  gemm_fkey<<<dim3(16, 32, 1), blk, 0, stream>>>(
      xn, wfk, gf, ssq_ffn, 4096, 1024, 32.0f);
  gemm_val<128, 2, false><<<dim3(8, 32, 2), blk, 0, stream>>>(
      gf, 0, wfvT, 0, p0, 18 * M1, ssq_ffn, 0, 1024, 4096, 2048, 2048, 0.0f, nullptr);
  fin_kernel<<<4096, blk, 0, stream>>>(p0, p1, x1, ssq_ffn, out);
}

// Round 10
// 401.469 us; speedup vs baseline: 1.0160x; 1.0160x over previous
//
#include <hip/hip_runtime.h>

typedef __bf16 bf16x8 __attribute__((ext_vector_type(8)));
typedef float f32x4 __attribute__((ext_vector_type(4)));
typedef unsigned short u16;

__device__ __forceinline__ float b2f(u16 u) {
  union { unsigned int i; float f; } v; v.i = ((unsigned int)u) << 16; return v.f;
}
__device__ __forceinline__ u16 f2b(float f) {
  union { float f; unsigned int i; } v; v.f = f;
  unsigned int x = v.i;
  x += 0x7fffu + ((x >> 16) & 1u);   // round-to-nearest-even
  return (u16)(x >> 16);
}
// fast tanh-gelu (validated R4-R6: absmax 0.047); exp2-folded: constants
// pre-multiplied by 1/ln2 so v_exp_f32 is used directly (saves 1 mul/gelu).
__device__ __forceinline__ float gelu_f(float x) {
  float x2 = x * x;
  float p = x * (2.3022083f + 0.1029434f * x2);   // 1.4426950*(1.5957691+0.0713548 x^2)
  float e = __builtin_amdgcn_exp2f(p);
  float r = __builtin_amdgcn_rcpf(1.0f + e);
  return x - x * r;
}
__device__ __forceinline__ void async16(const u16* g, u16* l) {
  __builtin_amdgcn_global_load_lds(
      (const __attribute__((address_space(1))) void*)g,
      (__attribute__((address_space(3))) void*)l, 16, 0, 0);
}
// XCD-aware supertile swizzle (R6; neutral at worst)
__device__ __forceinline__ void swz(int& bn, int& bm, int& bz) {
  int gx = (int)gridDim.x, gy = (int)gridDim.y;
  int flat = (int)(blockIdx.x + gridDim.x * (blockIdx.y + gridDim.y * blockIdx.z));
  int seq = flat >> 3;
  int nbm = gy >> 3;
  bm = (flat & 7) * nbm + seq % nbm;
  int rest = seq / nbm;
  bn = rest % gx;
  bz = rest / gx;
}

union U4 { uint4 u; u16 s[8]; };

// ---------------- prep: cvt9 + cvtT8 + ln1 fused into ONE launch ----------------
__global__ __launch_bounds__(256) void prep_kernel(
    const float* __restrict__ qk, const float* __restrict__ kk,
    const float* __restrict__ vk, const float* __restrict__ pk,
    const float* __restrict__ fk, u16* __restrict__ w, float* __restrict__ ssqz,
    const float* __restrict__ qv, const float* __restrict__ kv,
    const float* __restrict__ vv, const float* __restrict__ pv,
    const float* __restrict__ fv, u16* __restrict__ valsT, u16* __restrict__ fvT,
    const float* __restrict__ x, const float* __restrict__ lnw,
    const float* __restrict__ lnb, u16* __restrict__ xn) {
  __shared__ float t[32][33];
  int id = (int)blockIdx.x;
  int tid = threadIdx.x;
  if (id < 9216) {
    int z = id >> 10;
    int i = (id & 1023) * 256 + tid;
    if (z == 8) {
      if (i < 20480) ssqz[i] = 0.f;
      return;
    }
    const float* in = (z == 0) ? qk : (z == 1) ? kk : (z == 2) ? vk : (z == 3) ? pk
                      : fk + (size_t)(z - 4) * 1048576;
    u16* o = w + (size_t)z * 1048576;
    float4 f = ((const float4*)in)[i];
    ushort4 s;
    s.x = f2b(f.x); s.y = f2b(f.y); s.z = f2b(f.z); s.w = f2b(f.w);
    ((ushort4*)o)[i] = s;
  } else if (id < 17408) {
    int rid = id - 9216;
    int bc = rid & 31, br = (rid >> 5) & 31, z = rid >> 10;
    const float* in; u16* o; int Rout, rowoff;
    if (z < 4) {
      in = (z == 0) ? qv : (z == 1) ? kv : (z == 2) ? vv : pv;
      o = valsT + (size_t)z * 1048576; Rout = 1024; rowoff = 0;
    } else {
      in = fv + (size_t)(z - 4) * 1048576;
      o = fvT; Rout = 4096; rowoff = (z - 4) * 1024;
    }
    int r = tid >> 5, cc = tid & 31;
    #pragma unroll
    for (int i = 0; i < 4; ++i)
      t[r + i * 8][cc] = in[(size_t)(br * 32 + r + i * 8) * 1024 + bc * 32 + cc];
    __syncthreads();
    #pragma unroll
    for (int i = 0; i < 4; ++i)
      o[(size_t)(bc * 32 + r + i * 8) * Rout + rowoff + br * 32 + cc] = f2b(t[cc][r + i * 8]);
  } else {
    int wv = tid >> 6, lane = tid & 63;
    int row = (id - 17408) * 4 + wv;
    const float* xr = x + (size_t)row * 1024;
    float4 v[4];
    float s = 0.f, s2 = 0.f;
    #pragma unroll
    for (int i = 0; i < 4; ++i) {
      v[i] = ((const float4*)xr)[lane + 64 * i];
      s += v[i].x + v[i].y + v[i].z + v[i].w;
      s2 += v[i].x * v[i].x + v[i].y * v[i].y + v[i].z * v[i].z + v[i].w * v[i].w;
    }
    #pragma unroll
    for (int m = 1; m < 64; m <<= 1) { s += __shfl_xor(s, m); s2 += __shfl_xor(s2, m); }
    float mu = s * (1.0f / 1024.0f);
    float inv = rsqrtf(s2 * (1.0f / 1024.0f) - mu * mu + 1e-5f);
    u16* orow = xn + (size_t)row * 1024;
    #pragma unroll
    for (int i = 0; i < 4; ++i) {
      int c = (lane + 64 * i) * 4;
      ushort4 o;
      o.x = f2b((v[i].x - mu) * inv * lnw[c]     + lnb[c]);
      o.y = f2b((v[i].y - mu) * inv * lnw[c + 1] + lnb[c + 1]);
      o.z = f2b((v[i].z - mu) * inv * lnw[c + 2] + lnb[c + 2]);
      o.w = f2b((v[i].w - mu) * inv * lnw[c + 3] + lnb[c + 3]);
      ((ushort4*)orow)[lane + 64 * i] = o;
    }
  }
}

// ---------------- LayerNorm: wave-per-row, shuffle-only (ln2) ----------------
__global__ __launch_bounds__(256) void ln_kernel(const float* __restrict__ x,
    const float* __restrict__ w, const float* __restrict__ b, u16* __restrict__ out) {
  int wv = threadIdx.x >> 6, lane = threadIdx.x & 63;
  int row = blockIdx.x * 4 + wv;
  const float* xr = x + (size_t)row * 1024;
  float4 v[4];
  float s = 0.f, s2 = 0.f;
  #pragma unroll
  for (int i = 0; i < 4; ++i) {
    v[i] = ((const float4*)xr)[lane + 64 * i];
    s += v[i].x + v[i].y + v[i].z + v[i].w;
    s2 += v[i].x * v[i].x + v[i].y * v[i].y + v[i].z * v[i].z + v[i].w * v[i].w;
  }
  #pragma unroll
  for (int m = 1; m < 64; m <<= 1) { s += __shfl_xor(s, m); s2 += __shfl_xor(s2, m); }
  float mu = s * (1.0f / 1024.0f);
  float inv = rsqrtf(s2 * (1.0f / 1024.0f) - mu * mu + 1e-5f);
  u16* orow = out + (size_t)row * 1024;
  #pragma unroll
  for (int i = 0; i < 4; ++i) {
    int c = (lane + 64 * i) * 4;
    ushort4 o;
    o.x = f2b((v[i].x - mu) * inv * w[c]     + b[c]);
    o.y = f2b((v[i].y - mu) * inv * w[c + 1] + b[c + 1]);
    o.z = f2b((v[i].z - mu) * inv * w[c + 2] + b[c + 2]);
    o.w = f2b((v[i].w - mu) * inv * w[c + 3] + b[c + 3]);
    ((ushort4*)orow)[lane + 64 * i] = o;
  }
}

// ============ 3-deep counted-vmcnt 128-tile GEMMs (R5-exact symmetric pipeline) ============
template <int TM>
__global__ __launch_bounds__(256) void gemm_key(
    const u16* __restrict__ A, size_t sAz,
    const u16* __restrict__ B, size_t sBz,
    u16* __restrict__ C, size_t sCz,
    float* __restrict__ ssqb, size_t sSz,
    int N, int K, float alpha) {
  constexpr int AI = TM / 32;
  constexpr int G = TM / 64 + 2;                    // staging loads per thread
  __shared__ __align__(16) u16 As[3][TM * 32];
  __shared__ __align__(16) u16 Bs[3][128 * 32];
  int bn, bm, bz;
  swz(bn, bm, bz);
  const u16* Ab = A + (size_t)bz * sAz + (size_t)bm * TM * K;
  const u16* Bb = B + (size_t)bz * sBz + (size_t)bn * 128 * K;
  int tid = threadIdx.x, lane = tid & 63, wv = tid >> 6;
  int quad = lane >> 4, l16 = lane & 15;
  int lr = lane >> 2;
  int lcs = ((lane & 3) ^ ((lane >> 3) & 3)) * 8;   // pre-swizzled source col
  int rq = quad ^ ((l16 >> 1) & 3);                 // swizzled read slot
  int wm = wv >> 1, wn = wv & 1;
  int RB = wm * (TM / 2), CB = wn * 64;
  auto STAGE = [&](int k0, int buf) {
    #pragma unroll
    for (int t = 0; t < TM / 64; ++t) {
      int ia = wv * (TM / 64) + t;
      async16(Ab + (size_t)(ia * 16 + lr) * K + k0 + lcs, &As[buf][ia * 512]);
    }
    #pragma unroll
    for (int t = 0; t < 2; ++t) {
      int ib = wv * 2 + t;
      async16(Bb + (size_t)(ib * 16 + lr) * K + k0 + lcs, &Bs[buf][ib * 512]);
    }
  };
  f32x4 zero = {0.f, 0.f, 0.f, 0.f};
  f32x4 acc[AI][4];
  #pragma unroll
  for (int i = 0; i < AI; ++i)
    #pragma unroll
    for (int j = 0; j < 4; ++j) acc[i][j] = zero;
  int NT = K >> 5;
  STAGE(0, 0);
  STAGE(32, 1);
  int cur = 0;
  for (int t = 0; t < NT; ++t) {
    if (t + 1 < NT) asm volatile("s_waitcnt vmcnt(%0)" :: "i"(G) : "memory");
    else            asm volatile("s_waitcnt vmcnt(0)" ::: "memory");
    __builtin_amdgcn_s_barrier();
    __builtin_amdgcn_sched_barrier(0);
    bf16x8 af[AI], bf[4];
    #pragma unroll
    for (int i = 0; i < AI; ++i)
      af[i] = *(const bf16x8*)&As[cur][(RB + i * 16 + l16) * 32 + rq * 8];
    #pragma unroll
    for (int j = 0; j < 4; ++j)
      bf[j] = *(const bf16x8*)&Bs[cur][(CB + j * 16 + l16) * 32 + rq * 8];
    if (t + 2 < NT) {
      int nb = cur + 2; if (nb >= 3) nb -= 3;
      STAGE((t + 2) * 32, nb);
    }
    #pragma unroll
    for (int i = 0; i < AI; ++i)
      #pragma unroll
      for (int j = 0; j < 4; ++j)
        acc[i][j] = __builtin_amdgcn_mfma_f32_16x16x32_bf16(af[i], bf[j], acc[i][j], 0, 0, 0);
    cur = (cur == 2) ? 0 : cur + 1;
  }
  #pragma unroll
  for (int i = 0; i < AI; ++i) {
    int rbase = bm * TM + RB + i * 16 + quad * 4;
    float srow[4] = {0.f, 0.f, 0.f, 0.f};
    #pragma unroll
    for (int j = 0; j < 4; ++j) {
      int c = bn * 128 + CB + j * 16 + l16;
      #pragma unroll
      for (int reg = 0; reg < 4; ++reg) {
        float g = gelu_f(acc[i][j][reg] * alpha);
        srow[reg] += g * g;
        C[(size_t)bz * sCz + (size_t)(rbase + reg) * N + c] = f2b(g);
      }
    }
    #pragma unroll
    for (int reg = 0; reg < 4; ++reg) {
      float s = srow[reg];
      s += __shfl_xor(s, 1); s += __shfl_xor(s, 2);
      s += __shfl_xor(s, 4); s += __shfl_xor(s, 8);
      if (l16 == 0) atomicAdd(&ssqb[bz * sSz + rbase + reg], s);
    }
  }
}

// ---------------- FFN-key GEMM v2: 128x256 block, 64x128 wave tile ----------------
__global__ __launch_bounds__(256, 2) void gemm_fkey(
    const u16* __restrict__ A,
    const u16* __restrict__ B,
    u16* __restrict__ C,
    float* __restrict__ ssqb,
    int N, int K, float alpha) {
  __shared__ __align__(16) u16 As[2][128 * 32];
  __shared__ __align__(16) u16 Bs[3][256 * 32];
  int bn, bm, bz;
  swz(bn, bm, bz);
  const u16* Ab = A + (size_t)bm * 128 * K;
  const u16* Bb = B + (size_t)bn * 256 * K;
  int tid = threadIdx.x, lane = tid & 63, wv = tid >> 6;
  int quad = lane >> 4, l16 = lane & 15;
  int lr = lane >> 2;
  int lcs = ((lane & 3) ^ ((lane >> 3) & 3)) * 8;
  int rq = quad ^ ((l16 >> 1) & 3);
  int wm = wv >> 1, wn = wv & 1;
  int RB = wm * 64, CB = wn * 128;
  auto STAGE_A = [&](int k0, int buf) {
    #pragma unroll
    for (int t = 0; t < 2; ++t) {
      int ia = wv * 2 + t;
      async16(Ab + (size_t)(ia * 16 + lr) * K + k0 + lcs, &As[buf][ia * 512]);
    }
  };
  auto STAGE_B = [&](int k0, int buf) {
    #pragma unroll
    for (int t = 0; t < 4; ++t) {
      int ib = wv * 4 + t;
      async16(Bb + (size_t)(ib * 16 + lr) * K + k0 + lcs, &Bs[buf][ib * 512]);
    }
  };
  f32x4 zero = {0.f, 0.f, 0.f, 0.f};
  f32x4 acc[4][8];
  #pragma unroll
  for (int i = 0; i < 4; ++i)
    #pragma unroll
    for (int j = 0; j < 8; ++j) acc[i][j] = zero;
  int NT = K >> 5;
  STAGE_A(0, 0);
  STAGE_B(0, 0);
  STAGE_B(32, 1);
  int cb = 0;
  for (int t = 0; t < NT; ++t) {
    if (t + 1 < NT) asm volatile("s_waitcnt vmcnt(4)" ::: "memory");
    else            asm volatile("s_waitcnt vmcnt(0)" ::: "memory");
    __builtin_amdgcn_s_barrier();
    __builtin_amdgcn_sched_barrier(0);
    bf16x8 af[4], bf[8];
    #pragma unroll
    for (int i = 0; i < 4; ++i)
      af[i] = *(const bf16x8*)&As[t & 1][(RB + i * 16 + l16) * 32 + rq * 8];
    #pragma unroll
    for (int j = 0; j < 8; ++j)
      bf[j] = *(const bf16x8*)&Bs[cb][(CB + j * 16 + l16) * 32 + rq * 8];
    if (t + 1 < NT) STAGE_A((t + 1) * 32, (t + 1) & 1);
    if (t + 2 < NT) {
      int nb = cb + 2; if (nb >= 3) nb -= 3;
      STAGE_B((t + 2) * 32, nb);
    }
    #pragma unroll
    for (int i = 0; i < 4; ++i)
      #pragma unroll
      for (int j = 0; j < 8; ++j)
        acc[i][j] = __builtin_amdgcn_mfma_f32_16x16x32_bf16(af[i], bf[j], acc[i][j], 0, 0, 0);
    cb = (cb == 2) ? 0 : cb + 1;
  }
  #pragma unroll
  for (int i = 0; i < 4; ++i) {
    int rbase = bm * 128 + RB + i * 16 + quad * 4;
    float srow[4] = {0.f, 0.f, 0.f, 0.f};
    #pragma unroll
    for (int j = 0; j < 8; ++j) {
      int c = bn * 256 + CB + j * 16 + l16;
      #pragma unroll
      for (int reg = 0; reg < 4; ++reg) {
        float g = gelu_f(acc[i][j][reg] * alpha);
        srow[reg] += g * g;
        C[(size_t)(rbase + reg) * N + c] = f2b(g);
      }
    }
    #pragma unroll
    for (int reg = 0; reg < 4; ++reg) {
      float s = srow[reg];
      s += __shfl_xor(s, 1); s += __shfl_xor(s, 2);
      s += __shfl_xor(s, 4); s += __shfl_xor(s, 8);
      if (l16 == 0) atomicAdd(&ssqb[rbase + reg], s);
    }
  }
}

// ---------------- val-GEMM ----------------
template <int TM, int MODE, bool ROT>
__global__ __launch_bounds__(256) void gemm_val(
    const u16* __restrict__ A, size_t sAz,
    const u16* __restrict__ B, size_t sBz,
    void* __restrict__ C, size_t sCz,
    const float* __restrict__ ssqb, size_t sSz,
    int N, int K, int kzs, int klen, float sqrtP, const float* __restrict__ res) {
  constexpr int AI = TM / 32;
  constexpr int G = TM / 64 + 2;
  __shared__ __align__(16) u16 As[3][TM * 32];
  __shared__ __align__(16) u16 Bs[3][128 * 32];
  int bn, bm, bz;
  swz(bn, bm, bz);
  const u16* Ab = A + (size_t)bz * sAz + (size_t)bm * TM * K;
  const u16* Bb = B + (size_t)bz * sBz + (size_t)bn * 128 * K;
  int tid = threadIdx.x, lane = tid & 63, wv = tid >> 6;
  int quad = lane >> 4, l16 = lane & 15;
  int lr = lane >> 2;
  int lcs = ((lane & 3) ^ ((lane >> 3) & 3)) * 8;   // pre-swizzled source col
  int rq = quad ^ ((l16 >> 1) & 3);                 // swizzled read slot
  int wm = wv >> 1, wn = wv & 1;
  int RB = wm * (TM / 2), CB = wn * 64;
  int kb0 = bz * kzs;
  auto STAGE = [&](int k0, int buf) {
    #pragma unroll
    for (int t = 0; t < TM / 64; ++t) {
      int ia = wv * (TM / 64) + t;
      async16(Ab + (size_t)(ia * 16 + lr) * K + kb0 + k0 + lcs, &As[buf][ia * 512]);
    }
    #pragma unroll
    for (int t = 0; t < 2; ++t) {
      int ib = wv * 2 + t;
      async16(Bb + (size_t)(ib * 16 + lr) * K + kb0 + k0 + lcs, &Bs[buf][ib * 512]);
    }
  };
  f32x4 zero = {0.f, 0.f, 0.f, 0.f};
  f32x4 acc[AI][4];
  #pragma unroll
  for (int i = 0; i < AI; ++i)
    #pragma unroll
    for (int j = 0; j < 4; ++j) acc[i][j] = zero;
  int NT = klen >> 5;
  STAGE(0, 0);
  STAGE(32, 1);
  int cur = 0;
  for (int t = 0; t < NT; ++t) {
    if (t + 1 < NT) asm volatile("s_waitcnt vmcnt(%0)" :: "i"(G) : "memory");
    else            asm volatile("s_waitcnt vmcnt(0)" ::: "memory");
    __builtin_amdgcn_s_barrier();
    __builtin_amdgcn_sched_barrier(0);
    bf16x8 af[AI], bf[4];
    #pragma unroll
    for (int i = 0; i < AI; ++i)
      af[i] = *(const bf16x8*)&As[cur][(RB + i * 16 + l16) * 32 + rq * 8];
    #pragma unroll
    for (int j = 0; j < 4; ++j)
      bf[j] = *(const bf16x8*)&Bs[cur][(CB + j * 16 + l16) * 32 + rq * 8];
    if (t + 2 < NT) {
      int nb = cur + 2; if (nb >= 3) nb -= 3;
      STAGE((t + 2) * 32, nb);
    }
    #pragma unroll
    for (int i = 0; i < AI; ++i)
      #pragma unroll
      for (int j = 0; j < 4; ++j)
        acc[i][j] = __builtin_amdgcn_mfma_f32_16x16x32_bf16(af[i], bf[j], acc[i][j], 0, 0, 0);
    cur = (cur == 2) ? 0 : cur + 1;
  }
  #pragma unroll
  for (int i = 0; i < AI; ++i) {
    int rbase = bm * TM + RB + i * 16 + quad * 4;
    float sc[4];
    if (MODE < 2) {
      #pragma unroll
      for (int reg = 0; reg < 4; ++reg)
        sc[reg] = sqrtP * rsqrtf(ssqb[bz * sSz + rbase + reg]);
    }
    #pragma unroll
    for (int j = 0; j < 4; ++j) {
      int c = bn * 128 + CB + j * 16 + l16;
      #pragma unroll
      for (int reg = 0; reg < 4; ++reg) {
        float v = acc[i][j][reg];
        size_t idx = (size_t)(rbase + reg) * N + c;
        if (MODE == 0) {
          float vs = v * sc[reg];
          if (ROT && j == 0) {   // cols c%64 = l16 < 16: the rotary dims of each head
            float prt = __shfl_xor(vs, 8);
            if (bz < 2) {
              int seq = (rbase + reg) & 2047;
              float fr = exp2f((float)(l16 & 7) * -1.66096404744368f);  // 10000^-(i/8)
              float ang = (float)seq * fr;
              float c_ = __cosf(ang), s_ = __sinf(ang);
              vs = (l16 < 8) ? (vs * c_ - prt * s_) : (vs * c_ + prt * s_);
            }
          }
          ((u16*)C)[(size_t)bz * sCz + idx] = f2b(vs);
        } else if (MODE == 1) {
          ((float*)C)[idx] = v * sc[reg] + res[idx];
        } else {
          ((float*)C)[(size_t)bz * sCz + idx] = v;
        }
      }
    }
  }
}

// ---------------- per-head V transpose + PV-slot permutation ----------------
__global__ __launch_bounds__(256) void vt_kernel(const u16* __restrict__ vb,
                                                 u16* __restrict__ vT) {
  __shared__ __align__(16) u16 T[64][72];
  int st = blockIdx.x, bh = blockIdx.y;
  int b = bh >> 4, h = bh & 15;
  int tid = threadIdx.x;
  #pragma unroll
  for (int i = 0; i < 2; ++i) {
    int l = tid + 256 * i;
    int s = l >> 3, dc = l & 7;
    *(uint4*)&T[s][dc * 8] =
        *(const uint4*)(vb + (size_t)(b * 2048 + st * 64 + s) * 1024 + h * 64 + dc * 8);
  }
  __syncthreads();
  #pragma unroll
  for (int i = 0; i < 2; ++i) {
    int l = tid + 256 * i;
    int d = l >> 3, scid = l & 7;
    int blk = (scid >> 2) * 32;
    int qq = (scid & 3) * 4;
    U4 u;
    #pragma unroll
    for (int j = 0; j < 8; ++j)
      u.s[j] = T[blk + (j >> 2) * 16 + qq + (j & 3)][d];
    *(uint4*)(vT + ((size_t)bh * 64 + d) * 2048 + st * 64 + scid * 8) = u.u;
  }
}

// ---------------- fused causal attention, register-resident P, split-K balance ----------------
// gelu-l2norm attn is LINEARLY splittable over keys (no online max): partial
// oacc and ssq just add. Heavy q-tiles (qt>=17) are split into two blocks of
// <=16 key-tiles each, writing f32 partials; acmb_kernel combines. Grid
// 32x47, heavy-first (LPT): avg work/slot 16.5 iters vs old makespan 32.
// T2 XOR swizzle on LDS tiles (conflicts 0) as before.
__global__ __launch_bounds__(256) void attn_kernel(
    const u16* __restrict__ qb, const u16* __restrict__ kbp,
    const u16* __restrict__ vT, u16* __restrict__ ob,
    float* __restrict__ pP, float* __restrict__ ssqP) {
  __shared__ __align__(16) u16 Qs[64 * 64];       // 8 KB
  __shared__ __align__(16) u16 Ks[2][64 * 64];    // 16 KB
  __shared__ __align__(16) u16 Vts[2][64 * 64];   // 16 KB
  int bh = blockIdx.x;
  int y = (int)blockIdx.y;
  int qt, kb, ke, half = 0;
  bool part = false;
  if (y == 0) { qt = 16; kb = 0; ke = 17; }
  else if (y <= 30) {
    int s = y - 1;
    qt = 31 - (s >> 1); half = s & 1; part = true;
    int n = qt + 1, h = (n + 1) >> 1;
    kb = half ? h : 0; ke = half ? n : h;
  } else { qt = 46 - y; kb = 0; ke = qt + 1; }
  int b = bh >> 4, h16 = bh & 15;
  const u16* qp = qb + (size_t)b * 2048 * 1024 + h16 * 64;
  const u16* kp = kbp + (size_t)b * 2048 * 1024 + h16 * 64;
  const u16* vp = vT + (size_t)bh * 64 * 2048;
  int tid = threadIdx.x, lane = tid & 63, wv = tid >> 6;
  int quad = lane >> 4, l16 = lane & 15;
  int lr8 = lane >> 3;
  int lc8s = ((lane & 7) ^ lr8) * 8;              // pre-swizzled source column
  int rx = (l16 & 7) << 3;                        // read-side inverse XOR
  int MR = wv * 16;
  #pragma unroll
  for (int t = 0; t < 2; ++t) {
    int idx = wv * 2 + t;
    async16(qp + (size_t)(qt * 64 + idx * 8 + lr8) * 1024 + lc8s, &Qs[idx * 512]);
    async16(kp + (size_t)(kb * 64 + idx * 8 + lr8) * 1024 + lc8s, &Ks[0][idx * 512]);
    async16(vp + (size_t)(idx * 8 + lr8) * 2048 + kb * 64 + lc8s, &Vts[0][idx * 512]);
  }
  f32x4 zero = {0.f, 0.f, 0.f, 0.f};
  f32x4 oacc[4];
  #pragma unroll
  for (int dn = 0; dn < 4; ++dn) oacc[dn] = zero;
  float ssql = 0.f;
  bf16x8 bq0 = {}, bq1 = {};
  for (int kt = kb, cur = 0; kt < ke; ++kt, cur ^= 1) {
    __syncthreads();
    if (kt == kb) {
      bq0 = *(const bf16x8*)&Qs[((MR + l16) * 64 + quad * 8) ^ rx];
      bq1 = *(const bf16x8*)&Qs[((MR + l16) * 64 + 32 + quad * 8) ^ rx];
    }
    if (kt + 1 < ke) {
      #pragma unroll
      for (int t = 0; t < 2; ++t) {
        int idx = wv * 2 + t;
        async16(kp + (size_t)((kt + 1) * 64 + idx * 8 + lr8) * 1024 + lc8s, &Ks[cur ^ 1][idx * 512]);
        async16(vp + (size_t)(idx * 8 + lr8) * 2048 + (kt + 1) * 64 + lc8s, &Vts[cur ^ 1][idx * 512]);
      }
    }
    bool dg = (kt == qt);
    #pragma unroll
    for (int kc = 0; kc < 2; ++kc) {
      bf16x8 pf;
      #pragma unroll
      for (int snh = 0; snh < 2; ++snh) {
        int sn = kc * 2 + snh;
        bf16x8 ak0 = *(const bf16x8*)&Ks[cur][((sn * 16 + l16) * 64 + quad * 8) ^ rx];
        bf16x8 ak1 = *(const bf16x8*)&Ks[cur][((sn * 16 + l16) * 64 + 32 + quad * 8) ^ rx];
        f32x4 st = zero;
        st = __builtin_amdgcn_mfma_f32_16x16x32_bf16(ak0, bq0, st, 0, 0, 0);
        st = __builtin_amdgcn_mfma_f32_16x16x32_bf16(ak1, bq1, st, 0, 0, 0);
        #pragma unroll
        for (int r = 0; r < 4; ++r) {
          float gl = gelu_f(st[r] * 0.125f);
          if (dg && (sn * 16 + quad * 4 + r > MR + l16)) gl = 0.f;
          ssql += gl * gl;
          pf[snh * 4 + r] = (__bf16)gl;            // v_cvt_pk_bf16_f32 pairs
        }
      }
      #pragma unroll
      for (int dn = 0; dn < 4; ++dn) {
        bf16x8 bv = *(const bf16x8*)&Vts[cur][((dn * 16 + l16) * 64 + kc * 32 + quad * 8) ^ rx];
        oacc[dn] = __builtin_amdgcn_mfma_f32_16x16x32_bf16(pf, bv, oacc[dn], 0, 0, 0);
      }
    }
  }
  ssql += __shfl_xor(ssql, 16);
  ssql += __shfl_xor(ssql, 32);
  if (!part) {
    float sc = 45.254834f * rsqrtf(ssql);
    #pragma unroll
    for (int dn = 0; dn < 4; ++dn)
      #pragma unroll
      for (int r = 0; r < 4; ++r) {
        float scr = __shfl(sc, quad * 4 + r);
        int row = qt * 64 + MR + quad * 4 + r;
        int col = h16 * 64 + dn * 16 + l16;
        ob[(size_t)(b * 2048 + row) * 1024 + col] = f2b(oacc[dn][r] * scr);
      }
  } else {
    int sp = ((qt - 17) * 32 + bh) * 2 + half;
    if (lane < 16) ssqP[sp * 64 + MR + l16] = ssql;       // quad==0 lanes, row MR+l16
    float* po = pP + (size_t)sp * 4096;
    #pragma unroll
    for (int dn = 0; dn < 4; ++dn)
      #pragma unroll
      for (int r = 0; r < 4; ++r)
        po[(MR + quad * 4 + r) * 64 + dn * 16 + l16] = oacc[dn][r];
  }
}

// ---------------- attn combine: ob = (p0+p1) * 45.25/sqrt(ssq0+ssq1) ----------------
__global__ __launch_bounds__(256) void acmb_kernel(
    const float* __restrict__ pP, const float* __restrict__ ssqP,
    u16* __restrict__ ob) {
  int s = blockIdx.x;                       // 0..479
  int qt = 17 + (s >> 5), bh = s & 31;
  int b = bh >> 4, h = bh & 15;
  const float* p0 = pP + (size_t)(2 * s) * 4096;
  const float* p1 = p0 + 4096;
  int tid = threadIdx.x;
  int row = tid >> 2, c0 = (tid & 3) * 16;
  float sc = 45.254834f * rsqrtf(ssqP[(2 * s) * 64 + row] + ssqP[(2 * s + 1) * 64 + row]);
  u16* orow = ob + (size_t)(b * 2048 + qt * 64 + row) * 1024 + h * 64 + c0;
  #pragma unroll
  for (int i = 0; i < 16; i += 4) {
    float4 a = *(const float4*)(p0 + row * 64 + c0 + i);
    float4 c = *(const float4*)(p1 + row * 64 + c0 + i);
    ushort4 o;
    o.x = f2b((a.x + c.x) * sc); o.y = f2b((a.y + c.y) * sc);
    o.z = f2b((a.z + c.z) * sc); o.w = f2b((a.w + c.w) * sc);
    *(ushort4*)(orow + i) = o;
  }
}

// ---------------- finalize: out = x1 + 64*rsqrt(ssq)[row] * (p0+p1) ----------------
__global__ __launch_bounds__(256) void fin_kernel(
    const float* __restrict__ p0, const float* __restrict__ p1,
    const float* __restrict__ x1, const float* __restrict__ ssqf,
    float* __restrict__ out) {
  int row = blockIdx.x, t = threadIdx.x;
  float s = 64.0f * rsqrtf(ssqf[row]);
  size_t base = (size_t)row * 1024 + t * 4;
  float4 a = *(const float4*)(p0 + base);
  float4 b = *(const float4*)(p1 + base);
  float4 r = *(const float4*)(x1 + base);
  float4 o;
  o.x = r.x + s * (a.x + b.x); o.y = r.y + s * (a.y + b.y);
  o.z = r.z + s * (a.z + b.z); o.w = r.w + s * (a.w + b.w);
  *(float4*)(out + base) = o;
}

extern "C" void kernel_launch(void* const* d_in, const int* in_sizes, int n_in,
                              void* d_out, int out_size, void* d_ws, size_t ws_size,
                              hipStream_t stream) {
  const float* x    = (const float*)d_in[0];
  const float* ln1w = (const float*)d_in[1];
  const float* ln1b = (const float*)d_in[2];
  const float* ln2w = (const float*)d_in[3];
  const float* ln2b = (const float*)d_in[4];
  const float* qk   = (const float*)d_in[5];
  const float* qv   = (const float*)d_in[6];
  const float* kk   = (const float*)d_in[7];
  const float* kv   = (const float*)d_in[8];
  const float* vk   = (const float*)d_in[9];
  const float* vv   = (const float*)d_in[10];
  const float* pk   = (const float*)d_in[11];
  const float* pv   = (const float*)d_in[12];
  const float* fk   = (const float*)d_in[13];
  const float* fv   = (const float*)d_in[14];
  float* out = (float*)d_out;

  const size_t M1 = 1048576;
  u16* w = (u16*)d_ws;
  u16* wkeys  = w;                  // 0..3M qk,kk,vk | p0 covers 0..8M at ffn-val
  u16* wpk    = w + 3 * M1;
  u16* wfk    = w + 4 * M1;         // 4..8M
  u16* wvalsT = w + 8 * M1;         // 8..12M qvT,kvT,vvT,pvT
  u16* wpvT   = w + 11 * M1;
  u16* wfvT   = w + 12 * M1;        // 12..16M
  u16* xn     = w + 16 * M1;        // 16..20M
  u16* gq     = w + 20 * M1;        // qkv ghat z-stride 4M: 20,24,28
  u16* ob     = w + 20 * M1;        // attn out (gq z=0 dead)
  u16* vT     = w + 24 * M1;        // permuted V (gq z=1 dead)
  u16* gp     = w + 28 * M1;        // proj ghat (gq z=2 dead)
  u16* gf     = w + 20 * M1;        // ffn ghat 20..36M (ob/vT/gp dead)
  u16* qb     = w + 36 * M1;        // | p1 covers 36..44M at ffn-val
  u16* kb     = w + 40 * M1;
  u16* vb     = w + 44 * M1;
  float* ssq_qkv  = (float*)(w + 48 * M1);   // ssq region, never clobbered
  float* ssq_proj = ssq_qkv + 12288;
  float* ssq_ffn  = ssq_qkv + 16384;
  float* x1 = (float*)(w + 52 * M1);         // 52..60M
  float* p0 = (float*)w;
  float* p1 = (float*)(w + 36 * M1);
  // attn split-K partials: live ONLY between attn and acmb.
  // pP: 28..35.86M u16 (gp/gf region, dead during attn): 480*2*4096 f32 = 15.7MB
  // ssqP: start of x1 region (x1 written later at proj-val): 61440 f32
  float* pP   = (float*)(w + 28 * M1);
  float* ssqP = (float*)(w + 52 * M1);

  dim3 blk(256);
  prep_kernel<<<18432, blk, 0, stream>>>(
      qk, kk, vk, pk, fk, w, ssq_qkv,
      qv, kv, vv, pv, fv, wvalsT, wfvT,
      x, ln1w, ln1b, xn);

  gemm_key<128><<<dim3(8, 32, 3), blk, 0, stream>>>(
      xn, 0, wkeys, M1, gq, 4 * M1, ssq_qkv, 4096, 1024, 1024, 32.0f);
  gemm_val<128, 0, true><<<dim3(8, 32, 3), blk, 0, stream>>>(
      gq, 4 * M1, wvalsT, M1, qb, 4 * M1, ssq_qkv, 4096, 1024, 1024, 0, 1024, 32.0f, nullptr);

  vt_kernel<<<dim3(32, 32), blk, 0, stream>>>(vb, vT);
  attn_kernel<<<dim3(32, 47), blk, 0, stream>>>(qb, kb, vT, ob, pP, ssqP);
  acmb_kernel<<<480, blk, 0, stream>>>(pP, ssqP, ob);

  gemm_key<64><<<dim3(8, 64, 1), blk, 0, stream>>>(
      ob, 0, wpk, 0, gp, 0, ssq_proj, 0, 1024, 1024, 32.0f);
  gemm_val<64, 1, false><<<dim3(8, 64, 1), blk, 0, stream>>>(
      gp, 0, wpvT, 0, x1, 0, ssq_proj, 0, 1024, 1024, 0, 1024, 32.0f, x);

  ln_kernel<<<1024, blk, 0, stream>>>(x1, ln2w, ln2b, xn);
  gemm_fkey<<<dim3(16, 32, 1), blk, 0, stream>>>(
      xn, wfk, gf, ssq_ffn, 4096, 1024, 32.0f);
  gemm_val<128, 2, false><<<dim3(8, 32, 2), blk, 0, stream>>>(
      gf, 0, wfvT, 0, p0, 18 * M1, ssq_ffn, 0, 1024, 4096, 2048, 2048, 0.0f, nullptr);
  fin_kernel<<<4096, blk, 0, stream>>>(p0, p1, x1, ssq_ffn, out);
}